// Round 2
// baseline (310.615 us; speedup 1.0000x reference)
//
#include <hip/hip_runtime.h>

// DayAdapter: out[b,t,e] = softsign( x[b,t,:] @ W[day[b]] + bias[day[b]] )
// x: [64,1024,512] f32, day_ids: [64] i32, W: [24,512,512] f32, bias: [24,512] f32
//
// Round 4: occupancy/TLP attack. R3 post-mortem: counted-vmcnt pipelining gave
// +0% BW (3.23->3.31 TB/s) while costing occupancy -> the kernel is TLP-limited,
// not ILP-limited (memory-bound, needs ~6KB in-flight per CU; waves parked at
// barriers with empty queues). gfx950 unified VGPR+AGPR file: acc[4][4]=64 AGPR
// + 64 VGPR = 128 total = 4 waves/SIMD cap. Fix: halve the wave tile.
//   BM=64, BN=128, wave tile 32x64 -> acc[2][4]=32 AGPR (~96 total regs, 5 w/SIMD)
//   LDS 25.6 KB/block -> 5-6 blocks/CU -> 20 waves/CU (62.5% cap vs 50%).
//   Simple R2-style sync loop (it beat the pipelined R3). Grid 4096.

#define DIM 512
#define SEQ 1024
#define NB 64
#define NDAYS 24
#define BM 64
#define BN 128
#define BK 64
#define LDA (BK + 8)   // A row stride (bf16): +8 pad -> frag reads 2-way (free)

typedef __bf16 bf16x8 __attribute__((ext_vector_type(8)));
typedef __bf16 bf16x4 __attribute__((ext_vector_type(4)));
typedef float  f32x4  __attribute__((ext_vector_type(4)));

__device__ __forceinline__ void gll16(const void* g, void* l) {
    __builtin_amdgcn_global_load_lds(
        (const __attribute__((address_space(1))) unsigned int*)g,
        (__attribute__((address_space(3))) unsigned int*)l,
        16, 0, 0);
}

// ---- kernel 1: Wt[d][n][k] = bf16(W[d][k][n]) ----
__global__ __launch_bounds__(256)
void transpose_w_kernel(const float* __restrict__ W, __bf16* __restrict__ Wt) {
    __shared__ __bf16 T[32][33];
    const int d  = blockIdx.z;
    const int k0 = blockIdx.x * 32;
    const int n0 = blockIdx.y * 32;
    const int tx = threadIdx.x & 31;
    const int ty = threadIdx.x >> 5;   // 0..7
    const float* Wd = W + (size_t)d * DIM * DIM;
    #pragma unroll
    for (int i = 0; i < 4; ++i) {
        const int k = ty + i * 8;
        T[tx][k] = (__bf16)Wd[(size_t)(k0 + k) * DIM + n0 + tx];  // coalesced f32 read
    }
    __syncthreads();
    __bf16* Wtd = Wt + (size_t)d * DIM * DIM;
    #pragma unroll
    for (int i = 0; i < 4; ++i) {
        const int n = ty + i * 8;
        Wtd[(size_t)(n0 + n) * DIM + k0 + tx] = T[n][tx];         // coalesced bf16 write
    }
}

// ---- kernel 2: main GEMM + bias + softsign ----
__global__ __launch_bounds__(256, 5)
void day_adapter_kernel(const float* __restrict__ x,
                        const int*   __restrict__ day_ids,
                        const __bf16* __restrict__ Wt,
                        const float* __restrict__ bias,
                        float*       __restrict__ out)
{
    __shared__ __align__(16) __bf16 As[BM][LDA];    // 64 x 72 bf16 = 9216 B
    __shared__ __align__(16) __bf16 Bs[BN * BK];    // 16384 B, swizzled 16B chunks

    // XCD swizzle: L = xcdslot(3b) | ntile(2b) | hi(7b); the 4 ntiles of one
    // (m,b) share L mod 8 -> same XCD under round-robin dispatch (4096 % 8 == 0).
    const int L  = blockIdx.x;
    const int g  = (L >> 3) & 3;
    const int mb = (L & 7) | ((L >> 5) << 3);   // 0..1023
    const int m  = mb & 15;
    const int bb = mb >> 4;

    const int n0  = g * BN;
    const int m0  = m * BM;
    const int tid = threadIdx.x;
    const int day = day_ids[bb];

    const float*  xb  = x   + (size_t)bb  * SEQ * DIM + (size_t)m0 * DIM;
    const __bf16* Wtb = Wt  + (size_t)day * DIM * DIM + (size_t)n0 * DIM;
    float*        ob  = out + (size_t)bb  * SEQ * DIM + (size_t)m0 * DIM + n0;

    const int wave = tid >> 6;
    const int lane = tid & 63;
    const int wm   = (wave >> 1) * 32;   // 2 wave-rows x 32
    const int wn   = (wave & 1) * 64;    // 2 wave-cols x 64
    const int l15  = lane & 15;
    const int quad = lane >> 4;          // 0..3
    const int kq   = quad * 8;

    // A staging map: 4 float4s; row = tid>>2 (0..63), col = (tid&3)*4 + i*16
    const int a_row = tid >> 2;
    const int a_col = (tid & 3) * 4;

    char* BsB = (char*)Bs;

    f32x4 acc[2][4];
    const f32x4 zero = {0.f, 0.f, 0.f, 0.f};
    #pragma unroll
    for (int i = 0; i < 2; ++i)
        #pragma unroll
        for (int j = 0; j < 4; ++j) acc[i][j] = zero;

    for (int kk = 0; kk < DIM; kk += BK) {
        // -- B: async global->LDS, 4 x 16B per thread, swizzled chunk placement --
        #pragma unroll
        for (int p = 0; p < 4; ++p) {
            const int s  = p * 256 + tid;
            const int n  = s >> 3;
            const int cp = s & 7;
            const int c  = cp ^ (n & 7);
            gll16(Wtb + (size_t)n * DIM + kk + c * 8,
                  BsB + (size_t)(p * 256 + (tid & ~63)) * 16);
        }
        // -- A: f32 loads -> bf16 cvt -> 8B LDS writes --
        #pragma unroll
        for (int i = 0; i < 4; ++i) {
            const int col = a_col + i * 16;
            const float4 f = *(const float4*)(xb + (size_t)a_row * DIM + kk + col);
            bf16x4 v;
            v[0] = (__bf16)f.x; v[1] = (__bf16)f.y;
            v[2] = (__bf16)f.z; v[3] = (__bf16)f.w;
            *(bf16x4*)&As[a_row][col] = v;
        }
        __syncthreads();

        #pragma unroll
        for (int ks = 0; ks < 2; ++ks) {
            bf16x8 af[2], bfr[4];
            #pragma unroll
            for (int i = 0; i < 2; ++i)
                af[i] = *(const bf16x8*)&As[wm + i * 16 + l15][ks * 32 + kq];
            #pragma unroll
            for (int j = 0; j < 4; ++j) {
                const int n  = wn + j * 16 + l15;
                const int c  = ks * 4 + quad;
                const int cp = c ^ (n & 7);
                bfr[j] = *(const bf16x8*)&Bs[n * BK + cp * 8];
            }
            #pragma unroll
            for (int i = 0; i < 2; ++i)
                #pragma unroll
                for (int j = 0; j < 4; ++j)
                    acc[i][j] = __builtin_amdgcn_mfma_f32_16x16x32_bf16(
                        af[i], bfr[j], acc[i][j], 0, 0, 0);
        }
        __syncthreads();
    }

    // -- epilogue: bias + softsign --
    float bv[4];
    #pragma unroll
    for (int j = 0; j < 4; ++j)
        bv[j] = bias[(size_t)day * DIM + n0 + wn + j * 16 + l15];

    #pragma unroll
    for (int i = 0; i < 2; ++i) {
        const int rbase = wm + i * 16 + quad * 4;        // C/D: row = quad*4 + reg
        #pragma unroll
        for (int j = 0; j < 4; ++j) {
            const int col = wn + j * 16 + l15;           // C/D: col = lane&15
            #pragma unroll
            for (int r = 0; r < 4; ++r) {
                const float y = acc[i][j][r] + bv[j];
                ob[(size_t)(rbase + r) * DIM + col] = y / (1.0f + fabsf(y));
            }
        }
    }
}

extern "C" void kernel_launch(void* const* d_in, const int* in_sizes, int n_in,
                              void* d_out, int out_size, void* d_ws, size_t ws_size,
                              hipStream_t stream) {
    const float* x       = (const float*)d_in[0];
    const int*   day_ids = (const int*)  d_in[1];
    const float* W       = (const float*)d_in[2];
    const float* bias    = (const float*)d_in[3];
    float*       out     = (float*)d_out;
    __bf16*      Wt      = (__bf16*)d_ws;   // 24*512*512*2 = 12.58 MB

    dim3 tgrid(DIM / 32, DIM / 32, NDAYS);  // (16,16,24)
    transpose_w_kernel<<<tgrid, 256, 0, stream>>>(W, Wt);

    day_adapter_kernel<<<dim3(4096), 256, 0, stream>>>(x, day_ids, Wt, bias, out);
}